// Round 3
// baseline (472.784 us; speedup 1.0000x reference)
//
#include <hip/hip_runtime.h>

typedef __bf16 bf16x8 __attribute__((ext_vector_type(8)));
typedef float f32x4 __attribute__((ext_vector_type(4)));
typedef unsigned short ushort8v __attribute__((ext_vector_type(8)));

#define NB 16
#define NT 4096
#define NV 32000
#define ND 512
#define NH 1024
#define NSLOTS 256

__device__ __forceinline__ float b2f(unsigned short u) {
  unsigned int x = ((unsigned int)u) << 16;
  return __builtin_bit_cast(float, x);
}
__device__ __forceinline__ unsigned short f2b(float f) {
  unsigned int x = __builtin_bit_cast(unsigned int, f);
  unsigned int r = (x + 0x7FFFu + ((x >> 16) & 1u)) >> 16;
  return (unsigned short)r;
}

#define GLOAD_LDS16(g, l)                                                              \
  __builtin_amdgcn_global_load_lds((const __attribute__((address_space(1))) void*)(g), \
                                   (__attribute__((address_space(3))) void*)(l), 16, 0, 0)

// ---------------------------------------------------------------------------
// emb f32 -> bf16 (for gemm1 A gather)
// ---------------------------------------------------------------------------
__global__ __launch_bounds__(256) void cvt_kernel(const float* __restrict__ emb,
                                                  unsigned short* __restrict__ embb) {
  const long base = ((long)blockIdx.x * 256 + threadIdx.x) * 8;
  float4 a = *(const float4*)&emb[base];
  float4 b = *(const float4*)&emb[base + 4];
  ushort8v o;
  o[0] = f2b(a.x); o[1] = f2b(a.y); o[2] = f2b(a.z); o[3] = f2b(a.w);
  o[4] = f2b(b.x); o[5] = f2b(b.y); o[6] = f2b(b.z); o[7] = f2b(b.w);
  *(ushort8v*)&embb[base] = o;
}

// ---------------------------------------------------------------------------
// w1 (512x1024) f32 -> w1t bf16 (1024x512); w2 (1024x512) f32 -> w2t bf16 (512x1024)
// ---------------------------------------------------------------------------
__global__ __launch_bounds__(256) void wt_kernel(const float* __restrict__ w1,
                                                 const float* __restrict__ w2,
                                                 unsigned short* __restrict__ w1t,
                                                 unsigned short* __restrict__ w2t) {
  const int i = blockIdx.x * 256 + threadIdx.x;
  if (i < ND * NH) {
    const int n = i >> 9, k = i & 511;
    w1t[i] = f2b(w1[k * NH + n]);
  } else {
    const int j = i - ND * NH;
    const int n = j >> 10, k = j & 1023;
    w2t[j] = f2b(w2[k * ND + n]);
  }
}

// ---------------------------------------------------------------------------
// Tiled bf16 MFMA GEMM: Out[M x N slice] = act(A @ Bt^T + bias) -> bf16.
// A rows optionally gathered through seq. Tile 128x128, BK=64, 4 waves (2x2).
// ---------------------------------------------------------------------------
template <int KDIM, int NLD, bool GATHER, bool RELU>
__global__ __launch_bounds__(256) void gemm_kernel(
    const int* __restrict__ seq, const unsigned short* __restrict__ Abase,
    const unsigned short* __restrict__ Bt, const float* __restrict__ bias,
    unsigned short* __restrict__ Out) {
  __shared__ union {
    struct { unsigned short A[128 * 64]; unsigned short Bm[128 * 64]; } s;
    unsigned short C[128 * 128];
  } sm;
  const int tid = threadIdx.x;
  const int lane = tid & 63;
  const int w = tid >> 6;
  const int bn = blockIdx.x;
  const int bm = blockIdx.y;
  const int wm = w >> 1, wn = w & 1;
  const int lrow = lane >> 3;
  const int lcol = (lane & 7) * 8;
  const int segbase = w * 4;

  const unsigned short* asrc[4];
  const unsigned short* bsrc[4];
#pragma unroll
  for (int r = 0; r < 4; ++r) {
    const int seg = segbase + r;
    const int row = bm * 128 + seg * 8 + lrow;
    if constexpr (GATHER) {
      asrc[r] = Abase + (size_t)seq[row] * (size_t)KDIM + lcol;
    } else {
      asrc[r] = Abase + (size_t)row * (size_t)KDIM + lcol;
    }
    const int ncol = bn * 128 + seg * 8 + lrow;
    bsrc[r] = Bt + (size_t)ncol * (size_t)KDIM + lcol;
  }

  f32x4 acc[4][4] = {};

  for (int kt = 0; kt < KDIM / 64; ++kt) {
    __syncthreads();
#pragma unroll
    for (int r = 0; r < 4; ++r) {
      const int seg = segbase + r;
      GLOAD_LDS16(asrc[r] + kt * 64, &sm.s.A[seg * 512]);
      GLOAD_LDS16(bsrc[r] + kt * 64, &sm.s.Bm[seg * 512]);
    }
    __syncthreads();
    bf16x8 af[4][2], bfr[4][2];
#pragma unroll
    for (int m = 0; m < 4; ++m)
#pragma unroll
      for (int kk = 0; kk < 2; ++kk) {
        ushort8v t = *(const ushort8v*)&sm.s.A[(wm * 64 + m * 16 + (lane & 15)) * 64 + kk * 32 + (lane >> 4) * 8];
        af[m][kk] = __builtin_bit_cast(bf16x8, t);
      }
#pragma unroll
    for (int n = 0; n < 4; ++n)
#pragma unroll
      for (int kk = 0; kk < 2; ++kk) {
        ushort8v t = *(const ushort8v*)&sm.s.Bm[(wn * 64 + n * 16 + (lane & 15)) * 64 + kk * 32 + (lane >> 4) * 8];
        bfr[n][kk] = __builtin_bit_cast(bf16x8, t);
      }
#pragma unroll
    for (int m = 0; m < 4; ++m)
#pragma unroll
      for (int n = 0; n < 4; ++n)
#pragma unroll
        for (int kk = 0; kk < 2; ++kk)
          acc[m][n] = __builtin_amdgcn_mfma_f32_16x16x32_bf16(af[m][kk], bfr[n][kk], acc[m][n], 0, 0, 0);
  }

  __syncthreads();
  // Epilogue: bias (+relu), repack C through LDS for coalesced 16B stores.
#pragma unroll
  for (int m = 0; m < 4; ++m)
#pragma unroll
    for (int n = 0; n < 4; ++n) {
      const int col_l = wn * 64 + n * 16 + (lane & 15);
      const float bb = bias[bn * 128 + col_l];
      const int row_l0 = wm * 64 + m * 16 + ((lane >> 4) << 2);
#pragma unroll
      for (int i = 0; i < 4; ++i) {
        float v = acc[m][n][i] + bb;
        if constexpr (RELU) v = v > 0.f ? v : 0.f;
        sm.C[(row_l0 + i) * 128 + col_l] = f2b(v);
      }
    }
  __syncthreads();
#pragma unroll
  for (int r8 = 0; r8 < 8; ++r8) {
    const int chunk = r8 * 256 + tid;
    const int row = chunk >> 4;
    const int c8 = (chunk & 15) * 8;
    ushort8v v = *(const ushort8v*)&sm.C[row * 128 + c8];
    *(ushort8v*)&Out[(size_t)(bm * 128 + row) * (size_t)NLD + bn * 128 + c8] = v;
  }
}

// ---------------------------------------------------------------------------
// Fused residual + LayerNorm + gate (f32 math).
// x = emb[seq[t]] (f32) + FF (bf16); h -> H (bf16) and hlast (f32, last token);
// gate = sigmoid(h . wg + bg).
// ---------------------------------------------------------------------------
__global__ __launch_bounds__(256) void ln_gate_kernel(
    const int* __restrict__ seq, const float* __restrict__ emb,
    const unsigned short* __restrict__ FF, unsigned short* __restrict__ H,
    const float* __restrict__ ln_g, const float* __restrict__ ln_b,
    const float* __restrict__ wg, const float* __restrict__ bgp,
    float* __restrict__ gate, float* __restrict__ hlast) {
  const int lane = threadIdx.x & 63;
  const int w = threadIdx.x >> 6;
  const int t = blockIdx.x * 4 + w;
  const float* er = emb + (size_t)seq[t] * ND + lane * 8;
  ushort8v fv = *(const ushort8v*)&FF[(size_t)t * ND + lane * 8];
  float4 e0 = *(const float4*)er, e1 = *(const float4*)(er + 4);
  float x[8] = {b2f(fv[0]) + e0.x, b2f(fv[1]) + e0.y, b2f(fv[2]) + e0.z, b2f(fv[3]) + e0.w,
                b2f(fv[4]) + e1.x, b2f(fv[5]) + e1.y, b2f(fv[6]) + e1.z, b2f(fv[7]) + e1.w};
  float s = 0.f, sq = 0.f;
#pragma unroll
  for (int j = 0; j < 8; ++j) {
    s += x[j];
    sq += x[j] * x[j];
  }
#pragma unroll
  for (int o = 32; o; o >>= 1) {
    s += __shfl_xor(s, o);
    sq += __shfl_xor(sq, o);
  }
  const float mu = s * (1.f / 512.f);
  const float var = sq * (1.f / 512.f) - mu * mu;
  const float rs = rsqrtf(var + 1e-5f);
  float gd = 0.f;
  float h[8];
  ushort8v hv;
#pragma unroll
  for (int j = 0; j < 8; ++j) {
    const int col = lane * 8 + j;
    h[j] = (x[j] - mu) * rs * ln_g[col] + ln_b[col];
    hv[j] = f2b(h[j]);
    gd += h[j] * wg[col];
  }
  *(ushort8v*)&H[(size_t)t * ND + lane * 8] = hv;
#pragma unroll
  for (int o = 32; o; o >>= 1) gd += __shfl_xor(gd, o);
  if (lane == 0) gate[t] = 1.f / (1.f + expf(-(gd + bgp[0])));
  if ((t & (NT - 1)) == NT - 1) {
    const int b = t >> 12;
    float* hl = hlast + b * ND + lane * 8;
#pragma unroll
    for (int j = 0; j < 8; ++j) hl[j] = h[j];
  }
}

// ---------------------------------------------------------------------------
// Top-256 of 4096 per batch: radix threshold search on positive f32 bits.
// Deterministic, ties by lowest index (matches jax top_k's selected set).
// ---------------------------------------------------------------------------
__global__ __launch_bounds__(256) void topk_kernel(const float* __restrict__ gate,
                                                   int* __restrict__ topidx) {
  __shared__ unsigned int keys[NT];
  __shared__ int cnt;
  __shared__ int scan[256];
  const int b = blockIdx.x, tid = threadIdx.x;
  const float* g = gate + (size_t)b * NT;
  for (int i = tid; i < NT; i += 256) keys[i] = __builtin_bit_cast(unsigned int, g[i]);
  __syncthreads();
  unsigned int K = 0u;
  for (int bit = 31; bit >= 0; --bit) {
    const unsigned int cand = K | (1u << bit);
    if (tid == 0) cnt = 0;
    __syncthreads();
    int c = 0;
    for (int i = tid * 16; i < tid * 16 + 16; ++i) c += (keys[i] >= cand) ? 1 : 0;
    if (c) atomicAdd(&cnt, c);
    __syncthreads();
    const int cn = cnt;
    __syncthreads();
    if (cn >= NSLOTS) K = cand;
  }
  int gcnt = 0, ecnt = 0;
  for (int i = tid * 16; i < tid * 16 + 16; ++i) {
    gcnt += (keys[i] > K) ? 1 : 0;
    ecnt += (keys[i] == K) ? 1 : 0;
  }
  scan[tid] = gcnt;
  __syncthreads();
  for (int off = 1; off < 256; off <<= 1) {
    int v2 = (tid >= off) ? scan[tid - off] : 0;
    __syncthreads();
    scan[tid] += v2;
    __syncthreads();
  }
  const int gi = scan[tid];
  const int tot_gt = scan[255];
  __syncthreads();
  scan[tid] = ecnt;
  __syncthreads();
  for (int off = 1; off < 256; off <<= 1) {
    int v2 = (tid >= off) ? scan[tid - off] : 0;
    __syncthreads();
    scan[tid] += v2;
    __syncthreads();
  }
  const int ei = scan[tid];
  int gpos = gi - gcnt;
  int epos = tot_gt + (ei - ecnt);
  int* outp = topidx + b * NSLOTS;
  for (int i = tid * 16; i < tid * 16 + 16; ++i) {
    if (keys[i] > K) {
      outp[gpos++] = i;
    } else if (keys[i] == K) {
      if (epos < NSLOTS) outp[epos] = i;
      epos++;
    }
  }
}

// ---------------------------------------------------------------------------
// q = hlast @ wq + bq  (f32, one block per batch)
// ---------------------------------------------------------------------------
__global__ __launch_bounds__(512) void q_kernel(const float* __restrict__ hlast,
                                                const float* __restrict__ wq,
                                                const float* __restrict__ bq,
                                                float* __restrict__ q) {
  __shared__ float hl[512];
  const int b = blockIdx.x, tid = threadIdx.x;
  hl[tid] = hlast[b * 512 + tid];
  __syncthreads();
  float acc = bq[tid];
  for (int d = 0; d < 512; ++d) acc += hl[d] * wq[d * 512 + tid];
  q[b * 512 + tid] = acc;
}

// ---------------------------------------------------------------------------
// scores -> softmax -> ctx  (one block per batch; H is bf16)
// ---------------------------------------------------------------------------
__global__ __launch_bounds__(256) void attn_kernel(const unsigned short* __restrict__ H,
                                                   const float* __restrict__ q,
                                                   const int* __restrict__ topidx,
                                                   float* __restrict__ ctx) {
  __shared__ float qs[512];
  __shared__ float attn[256];
  __shared__ int idxs[256];
  __shared__ float red[4];
  const int b = blockIdx.x, tid = threadIdx.x;
  const int lane = tid & 63, wv = tid >> 6;
  qs[tid] = q[b * 512 + tid];
  qs[256 + tid] = q[b * 512 + 256 + tid];
  idxs[tid] = topidx[b * 256 + tid];
  __syncthreads();
  const unsigned short* hr = H + ((size_t)b * NT + idxs[tid]) * ND;
  float sc = 0.f;
  for (int d0 = 0; d0 < 512; d0 += 8) {
    ushort8v hv = *(const ushort8v*)&hr[d0];
#pragma unroll
    for (int j = 0; j < 8; ++j) sc += b2f(hv[j]) * qs[d0 + j];
  }
  float m = sc;
#pragma unroll
  for (int o = 32; o; o >>= 1) m = fmaxf(m, __shfl_xor(m, o));
  if (lane == 0) red[wv] = m;
  __syncthreads();
  m = fmaxf(fmaxf(red[0], red[1]), fmaxf(red[2], red[3]));
  __syncthreads();
  const float e = expf(sc - m);
  float ssum = e;
#pragma unroll
  for (int o = 32; o; o >>= 1) ssum += __shfl_xor(ssum, o);
  if (lane == 0) red[wv] = ssum;
  __syncthreads();
  ssum = red[0] + red[1] + red[2] + red[3];
  attn[tid] = e / ssum;
  __syncthreads();
  for (int d = tid; d < 512; d += 256) {
    float c = 0.f;
    for (int k = 0; k < 256; ++k) c += attn[k] * b2f(H[((size_t)b * NT + idxs[k]) * ND + d]);
    ctx[b * 512 + d] = c;
  }
}

// ---------------------------------------------------------------------------
// out = ctx @ wo + bo  (f32; each thread owns one vocab column, all 16 batches)
// ---------------------------------------------------------------------------
__global__ __launch_bounds__(256) void out_kernel(const float* __restrict__ ctx,
                                                  const float* __restrict__ wo,
                                                  const float* __restrict__ bo,
                                                  float* __restrict__ out) {
  __shared__ float cs[16 * 512];
  const int tid = threadIdx.x;
  const int v = blockIdx.x * 256 + tid;
  for (int i = tid; i < 16 * 512; i += 256) cs[i] = ctx[i];
  __syncthreads();
  float acc[16] = {};
  for (int d = 0; d < 512; ++d) {
    const float wv = wo[(size_t)d * NV + v];
#pragma unroll
    for (int bb = 0; bb < 16; ++bb) acc[bb] += cs[bb * 512 + d] * wv;
  }
  const float bov = bo[v];
#pragma unroll
  for (int bb = 0; bb < 16; ++bb) out[(size_t)bb * NV + v] = acc[bb] + bov;
}

// ---------------------------------------------------------------------------
// Workspace layout (byte offsets; total 194.0 MiB — under the round-0-proven
// footprint of 194.33 MiB):
//   A1     @ 0          : 65536x1024 bf16 = 128 MiB (gemm1 out; later aliased as H 64 MiB)
//   region @ 128 MiB    : 64 MiB — embb (31.25 MiB, dead after gemm1), then FF bf16 (64 MiB)
//   w1t    @ 192 MiB    : 1 MiB — dead after gemm1; aliased later by gate/topidx/hlast/q/ctx (368 KB)
//   w2t    @ 193 MiB    : 1 MiB — dead after gemm2
// ---------------------------------------------------------------------------
extern "C" void kernel_launch(void* const* d_in, const int* in_sizes, int n_in,
                              void* d_out, int out_size, void* d_ws, size_t ws_size,
                              hipStream_t stream) {
  const int* seq = (const int*)d_in[0];
  const float* emb = (const float*)d_in[1];
  const float* w1 = (const float*)d_in[2];
  const float* b1 = (const float*)d_in[3];
  const float* w2 = (const float*)d_in[4];
  const float* b2 = (const float*)d_in[5];
  const float* ln_g = (const float*)d_in[6];
  const float* ln_b = (const float*)d_in[7];
  const float* wg = (const float*)d_in[8];
  const float* bg = (const float*)d_in[9];
  const float* wq = (const float*)d_in[10];
  const float* bq = (const float*)d_in[11];
  const float* wo = (const float*)d_in[12];
  const float* bo = (const float*)d_in[13];
  float* out = (float*)d_out;

  char* ws = (char*)d_ws;
  unsigned short* A1 = (unsigned short*)ws;                       // 128 MiB
  unsigned short* region = (unsigned short*)(ws + ((size_t)128 << 20));
  unsigned short* embb = region;                                  // 31.25 MiB (phase 1)
  unsigned short* FF = region;                                    // 64 MiB (phase 2)
  unsigned short* w1t = (unsigned short*)(ws + ((size_t)192 << 20));
  unsigned short* w2t = (unsigned short*)(ws + ((size_t)193 << 20));
  // small buffers alias w1t (dead after gemm1):
  char* sb = ws + ((size_t)192 << 20);
  float* gate = (float*)sb;                                       // 256 KiB
  int* topidx = (int*)(sb + 262144);                              // 16 KiB
  float* hlast = (float*)(sb + 262144 + 16384);                   // 32 KiB
  float* qbuf = (float*)(sb + 262144 + 16384 + 32768);            // 32 KiB
  float* ctxbuf = (float*)(sb + 262144 + 16384 + 65536);          // 32 KiB
  unsigned short* H = A1;                                         // A1 dead after gemm2

  cvt_kernel<<<8000, 256, 0, stream>>>(emb, embb);
  wt_kernel<<<4096, 256, 0, stream>>>(w1, w2, w1t, w2t);
  gemm_kernel<512, 1024, true, true>
      <<<dim3(8, 512), 256, 0, stream>>>(seq, embb, w1t, b1, A1);
  gemm_kernel<1024, 512, false, false>
      <<<dim3(4, 512), 256, 0, stream>>>(nullptr, A1, w2t, b2, FF);
  ln_gate_kernel<<<16384, 256, 0, stream>>>(seq, emb, FF, H, ln_g, ln_b, wg, bg, gate, hlast);
  topk_kernel<<<16, 256, 0, stream>>>(gate, topidx);
  q_kernel<<<16, 512, 0, stream>>>(hlast, wq, bq, qbuf);
  attn_kernel<<<16, 256, 0, stream>>>(H, qbuf, topidx, ctxbuf);
  out_kernel<<<125, 256, 0, stream>>>(ctxbuf, wo, bo, out);
}

// Round 4
// 431.933 us; speedup vs baseline: 1.0946x; 1.0946x over previous
//
#include <hip/hip_runtime.h>

typedef __bf16 bf16x8 __attribute__((ext_vector_type(8)));
typedef float f32x4 __attribute__((ext_vector_type(4)));
typedef unsigned short ushort8v __attribute__((ext_vector_type(8)));

#define NB 16
#define NT 4096
#define NV 32000
#define ND 512
#define NH 1024
#define NSLOTS 256

__device__ __forceinline__ float b2f(unsigned short u) {
  unsigned int x = ((unsigned int)u) << 16;
  return __builtin_bit_cast(float, x);
}
__device__ __forceinline__ unsigned short f2b(float f) {
  unsigned int x = __builtin_bit_cast(unsigned int, f);
  unsigned int r = (x + 0x7FFFu + ((x >> 16) & 1u)) >> 16;
  return (unsigned short)r;
}

#define GLOAD_LDS16(g, l)                                                              \
  __builtin_amdgcn_global_load_lds((const __attribute__((address_space(1))) void*)(g), \
                                   (__attribute__((address_space(3))) void*)(l), 16, 0, 0)

// ---------------------------------------------------------------------------
// emb f32 -> bf16 (for gemm1 A gather)
// ---------------------------------------------------------------------------
__global__ __launch_bounds__(256) void cvt_kernel(const float* __restrict__ emb,
                                                  unsigned short* __restrict__ embb) {
  const long base = ((long)blockIdx.x * 256 + threadIdx.x) * 8;
  float4 a = *(const float4*)&emb[base];
  float4 b = *(const float4*)&emb[base + 4];
  ushort8v o;
  o[0] = f2b(a.x); o[1] = f2b(a.y); o[2] = f2b(a.z); o[3] = f2b(a.w);
  o[4] = f2b(b.x); o[5] = f2b(b.y); o[6] = f2b(b.z); o[7] = f2b(b.w);
  *(ushort8v*)&embb[base] = o;
}

// ---------------------------------------------------------------------------
// w1 (512x1024) f32 -> w1t bf16 (1024x512); w2 (1024x512) f32 -> w2t bf16 (512x1024)
// ---------------------------------------------------------------------------
__global__ __launch_bounds__(256) void wt_kernel(const float* __restrict__ w1,
                                                 const float* __restrict__ w2,
                                                 unsigned short* __restrict__ w1t,
                                                 unsigned short* __restrict__ w2t) {
  const int i = blockIdx.x * 256 + threadIdx.x;
  if (i < ND * NH) {
    const int n = i >> 9, k = i & 511;
    w1t[i] = f2b(w1[k * NH + n]);
  } else {
    const int j = i - ND * NH;
    const int n = j >> 10, k = j & 1023;
    w2t[j] = f2b(w2[k * ND + n]);
  }
}

// ---------------------------------------------------------------------------
// Tiled bf16 MFMA GEMM: Out[M x N slice] = act(A @ Bt^T + bias) -> bf16.
// Tile 128x128, BK=32 double-buffered, XOR-swizzled LDS (both-sides: linear
// global_load_lds dest + pre-swizzled global src; swizzled ds_read),
// XCD-aware block swizzle. 4 waves (2x2).
// ---------------------------------------------------------------------------
template <int KDIM, int NLD, int NBN, bool GATHER, bool RELU>
__global__ __launch_bounds__(256) void gemm_kernel(
    const int* __restrict__ seq, const unsigned short* __restrict__ Abase,
    const unsigned short* __restrict__ Bt, const float* __restrict__ bias,
    unsigned short* __restrict__ Out) {
  __shared__ union {
    unsigned short AB[2][2][128 * 32];  // [buf][A/B][row*32 + chunk*8]
    unsigned short C[128 * 136];        // padded: 272 B/row, 16B-aligned
  } sm;
  const int tid = threadIdx.x;
  const int lane = tid & 63;
  const int w = tid >> 6;

  // XCD-aware bijective swizzle (gridDim.x % 8 == 0 for both gemms)
  const int id = blockIdx.x;
  const int swz = (id & 7) * (gridDim.x >> 3) + (id >> 3);
  const int bm = swz / NBN;
  const int bn = swz % NBN;

  const int wm = w >> 1, wn = w & 1;

  // Staging: wave w stages row-groups {2w,2w+1} of A and B.
  // lane l -> row_in_grp = l>>2, dst chunk = l&3 (HW-linear), src chunk
  // pre-swizzled so LDS slot (row, c) holds global chunk c ^ ((row>>1)&3).
  const int rgrp = lane >> 2;
  const int schunk = (lane & 3) ^ ((lane >> 3) & 3);
  const unsigned short* aptr[2];
  const unsigned short* bptr[2];
#pragma unroll
  for (int r = 0; r < 2; ++r) {
    const int grp = w * 2 + r;
    const int arow = bm * 128 + grp * 16 + rgrp;
    if constexpr (GATHER)
      aptr[r] = Abase + (size_t)seq[arow] * (size_t)KDIM + schunk * 8;
    else
      aptr[r] = Abase + (size_t)arow * (size_t)KDIM + schunk * 8;
    const int brow = bn * 128 + grp * 16 + rgrp;
    bptr[r] = Bt + (size_t)brow * (size_t)KDIM + schunk * 8;
  }

  // Fragment read offsets (shorts), same swizzle on the read side.
  const int fr = lane & 15;
  const int fhi = lane >> 4;
  const int fsw = (fr >> 1) & 3;
  const int fchunk = (fhi ^ fsw) * 8;
  int aoff[4], boff[4];
#pragma unroll
  for (int m = 0; m < 4; ++m) aoff[m] = (wm * 64 + m * 16 + fr) * 32 + fchunk;
#pragma unroll
  for (int n = 0; n < 4; ++n) boff[n] = (wn * 64 + n * 16 + fr) * 32 + fchunk;

  f32x4 acc[4][4] = {};

  auto stage = [&](int buf, int kt) {
#pragma unroll
    for (int r = 0; r < 2; ++r) {
      const int grp = w * 2 + r;
      GLOAD_LDS16(aptr[r] + kt * 32, &sm.AB[buf][0][grp * 512]);
      GLOAD_LDS16(bptr[r] + kt * 32, &sm.AB[buf][1][grp * 512]);
    }
  };

  stage(0, 0);
  __syncthreads();
  constexpr int NKT = KDIM / 32;
  for (int kt = 0; kt < NKT; ++kt) {
    const int cur = kt & 1;
    if (kt + 1 < NKT) stage(cur ^ 1, kt + 1);  // prefetch flies under compute
    bf16x8 af[4], bfr[4];
#pragma unroll
    for (int m = 0; m < 4; ++m)
      af[m] = __builtin_bit_cast(bf16x8, *(const ushort8v*)&sm.AB[cur][0][aoff[m]]);
#pragma unroll
    for (int n = 0; n < 4; ++n)
      bfr[n] = __builtin_bit_cast(bf16x8, *(const ushort8v*)&sm.AB[cur][1][boff[n]]);
#pragma unroll
    for (int m = 0; m < 4; ++m)
#pragma unroll
      for (int n = 0; n < 4; ++n)
        acc[m][n] = __builtin_amdgcn_mfma_f32_16x16x32_bf16(af[m], bfr[n], acc[m][n], 0, 0, 0);
    __syncthreads();
  }

  // Epilogue: bias (+relu), repack C through padded LDS for 16B stores.
#pragma unroll
  for (int m = 0; m < 4; ++m)
#pragma unroll
    for (int n = 0; n < 4; ++n) {
      const int col_l = wn * 64 + n * 16 + fr;
      const float bb = bias[bn * 128 + col_l];
      const int row_l0 = wm * 64 + m * 16 + (fhi << 2);
#pragma unroll
      for (int i = 0; i < 4; ++i) {
        float v = acc[m][n][i] + bb;
        if constexpr (RELU) v = fmaxf(v, 0.f);
        sm.C[(row_l0 + i) * 136 + col_l] = f2b(v);
      }
    }
  __syncthreads();
#pragma unroll
  for (int r8 = 0; r8 < 8; ++r8) {
    const int chunk = r8 * 256 + tid;
    const int row = chunk >> 4;
    const int c8 = (chunk & 15) * 8;
    ushort8v v = *(const ushort8v*)&sm.C[row * 136 + c8];
    *(ushort8v*)&Out[(size_t)(bm * 128 + row) * (size_t)NLD + bn * 128 + c8] = v;
  }
}

// ---------------------------------------------------------------------------
// Fused residual + LayerNorm + gate (f32 math).
// ---------------------------------------------------------------------------
__global__ __launch_bounds__(256) void ln_gate_kernel(
    const int* __restrict__ seq, const float* __restrict__ emb,
    const unsigned short* __restrict__ FF, unsigned short* __restrict__ H,
    const float* __restrict__ ln_g, const float* __restrict__ ln_b,
    const float* __restrict__ wg, const float* __restrict__ bgp,
    float* __restrict__ gate, float* __restrict__ hlast) {
  const int lane = threadIdx.x & 63;
  const int w = threadIdx.x >> 6;
  const int t = blockIdx.x * 4 + w;
  const float* er = emb + (size_t)seq[t] * ND + lane * 8;
  ushort8v fv = *(const ushort8v*)&FF[(size_t)t * ND + lane * 8];
  float4 e0 = *(const float4*)er, e1 = *(const float4*)(er + 4);
  float x[8] = {b2f(fv[0]) + e0.x, b2f(fv[1]) + e0.y, b2f(fv[2]) + e0.z, b2f(fv[3]) + e0.w,
                b2f(fv[4]) + e1.x, b2f(fv[5]) + e1.y, b2f(fv[6]) + e1.z, b2f(fv[7]) + e1.w};
  float s = 0.f, sq = 0.f;
#pragma unroll
  for (int j = 0; j < 8; ++j) {
    s += x[j];
    sq += x[j] * x[j];
  }
#pragma unroll
  for (int o = 32; o; o >>= 1) {
    s += __shfl_xor(s, o);
    sq += __shfl_xor(sq, o);
  }
  const float mu = s * (1.f / 512.f);
  const float var = sq * (1.f / 512.f) - mu * mu;
  const float rs = rsqrtf(var + 1e-5f);
  float gd = 0.f;
  float h[8];
  ushort8v hv;
#pragma unroll
  for (int j = 0; j < 8; ++j) {
    const int col = lane * 8 + j;
    h[j] = (x[j] - mu) * rs * ln_g[col] + ln_b[col];
    hv[j] = f2b(h[j]);
    gd += h[j] * wg[col];
  }
  *(ushort8v*)&H[(size_t)t * ND + lane * 8] = hv;
#pragma unroll
  for (int o = 32; o; o >>= 1) gd += __shfl_xor(gd, o);
  if (lane == 0) gate[t] = 1.f / (1.f + expf(-(gd + bgp[0])));
  if ((t & (NT - 1)) == NT - 1) {
    const int b = t >> 12;
    float* hl = hlast + b * ND + lane * 8;
#pragma unroll
    for (int j = 0; j < 8; ++j) hl[j] = h[j];
  }
}

// ---------------------------------------------------------------------------
// Top-256 of 4096 per batch: radix threshold search on positive f32 bits.
// Deterministic, ties by lowest index.
// ---------------------------------------------------------------------------
__global__ __launch_bounds__(256) void topk_kernel(const float* __restrict__ gate,
                                                   int* __restrict__ topidx) {
  __shared__ unsigned int keys[NT];
  __shared__ int cnt;
  __shared__ int scan[256];
  const int b = blockIdx.x, tid = threadIdx.x;
  const float* g = gate + (size_t)b * NT;
  for (int i = tid; i < NT; i += 256) keys[i] = __builtin_bit_cast(unsigned int, g[i]);
  __syncthreads();
  unsigned int K = 0u;
  for (int bit = 31; bit >= 0; --bit) {
    const unsigned int cand = K | (1u << bit);
    if (tid == 0) cnt = 0;
    __syncthreads();
    int c = 0;
    for (int i = tid * 16; i < tid * 16 + 16; ++i) c += (keys[i] >= cand) ? 1 : 0;
    if (c) atomicAdd(&cnt, c);
    __syncthreads();
    const int cn = cnt;
    __syncthreads();
    if (cn >= NSLOTS) K = cand;
  }
  int gcnt = 0, ecnt = 0;
  for (int i = tid * 16; i < tid * 16 + 16; ++i) {
    gcnt += (keys[i] > K) ? 1 : 0;
    ecnt += (keys[i] == K) ? 1 : 0;
  }
  scan[tid] = gcnt;
  __syncthreads();
  for (int off = 1; off < 256; off <<= 1) {
    int v2 = (tid >= off) ? scan[tid - off] : 0;
    __syncthreads();
    scan[tid] += v2;
    __syncthreads();
  }
  const int gi = scan[tid];
  const int tot_gt = scan[255];
  __syncthreads();
  scan[tid] = ecnt;
  __syncthreads();
  for (int off = 1; off < 256; off <<= 1) {
    int v2 = (tid >= off) ? scan[tid - off] : 0;
    __syncthreads();
    scan[tid] += v2;
    __syncthreads();
  }
  const int ei = scan[tid];
  int gpos = gi - gcnt;
  int epos = tot_gt + (ei - ecnt);
  int* outp = topidx + b * NSLOTS;
  for (int i = tid * 16; i < tid * 16 + 16; ++i) {
    if (keys[i] > K) {
      outp[gpos++] = i;
    } else if (keys[i] == K) {
      if (epos < NSLOTS) outp[epos] = i;
      epos++;
    }
  }
}

// ---------------------------------------------------------------------------
// q = hlast @ wq + bq  (f32, one block per batch)
// ---------------------------------------------------------------------------
__global__ __launch_bounds__(512) void q_kernel(const float* __restrict__ hlast,
                                                const float* __restrict__ wq,
                                                const float* __restrict__ bq,
                                                float* __restrict__ q) {
  __shared__ float hl[512];
  const int b = blockIdx.x, tid = threadIdx.x;
  hl[tid] = hlast[b * 512 + tid];
  __syncthreads();
  float acc = bq[tid];
  for (int d = 0; d < 512; ++d) acc += hl[d] * wq[d * 512 + tid];
  q[b * 512 + tid] = acc;
}

// ---------------------------------------------------------------------------
// scores -> softmax -> ctx  (one block per batch; H is bf16)
// ---------------------------------------------------------------------------
__global__ __launch_bounds__(256) void attn_kernel(const unsigned short* __restrict__ H,
                                                   const float* __restrict__ q,
                                                   const int* __restrict__ topidx,
                                                   float* __restrict__ ctx) {
  __shared__ float qs[512];
  __shared__ float attn[256];
  __shared__ int idxs[256];
  __shared__ float red[4];
  const int b = blockIdx.x, tid = threadIdx.x;
  const int lane = tid & 63, wv = tid >> 6;
  qs[tid] = q[b * 512 + tid];
  qs[256 + tid] = q[b * 512 + 256 + tid];
  idxs[tid] = topidx[b * 256 + tid];
  __syncthreads();
  const unsigned short* hr = H + ((size_t)b * NT + idxs[tid]) * ND;
  float sc = 0.f;
  for (int d0 = 0; d0 < 512; d0 += 8) {
    ushort8v hv = *(const ushort8v*)&hr[d0];
#pragma unroll
    for (int j = 0; j < 8; ++j) sc += b2f(hv[j]) * qs[d0 + j];
  }
  float m = sc;
#pragma unroll
  for (int o = 32; o; o >>= 1) m = fmaxf(m, __shfl_xor(m, o));
  if (lane == 0) red[wv] = m;
  __syncthreads();
  m = fmaxf(fmaxf(red[0], red[1]), fmaxf(red[2], red[3]));
  __syncthreads();
  const float e = expf(sc - m);
  float ssum = e;
#pragma unroll
  for (int o = 32; o; o >>= 1) ssum += __shfl_xor(ssum, o);
  if (lane == 0) red[wv] = ssum;
  __syncthreads();
  ssum = red[0] + red[1] + red[2] + red[3];
  attn[tid] = e / ssum;
  __syncthreads();
  for (int d = tid; d < 512; d += 256) {
    float c = 0.f;
    for (int k = 0; k < 256; ++k) c += attn[k] * b2f(H[((size_t)b * NT + idxs[k]) * ND + d]);
    ctx[b * 512 + d] = c;
  }
}

// ---------------------------------------------------------------------------
// out = ctx @ wo + bo  (f32; each thread owns one vocab column, all 16 batches)
// ---------------------------------------------------------------------------
__global__ __launch_bounds__(256) void out_kernel(const float* __restrict__ ctx,
                                                  const float* __restrict__ wo,
                                                  const float* __restrict__ bo,
                                                  float* __restrict__ out) {
  __shared__ float cs[16 * 512];
  const int tid = threadIdx.x;
  const int v = blockIdx.x * 256 + tid;
  for (int i = tid; i < 16 * 512; i += 256) cs[i] = ctx[i];
  __syncthreads();
  float acc[16] = {};
  for (int d = 0; d < 512; ++d) {
    const float wv = wo[(size_t)d * NV + v];
#pragma unroll
    for (int bb = 0; bb < 16; ++bb) acc[bb] += cs[bb * 512 + d] * wv;
  }
  const float bov = bo[v];
#pragma unroll
  for (int bb = 0; bb < 16; ++bb) out[(size_t)bb * NV + v] = acc[bb] + bov;
}

// ---------------------------------------------------------------------------
// Workspace layout (byte offsets; total 194.0 MiB):
//   A1     @ 0          : 65536x1024 bf16 = 128 MiB (gemm1 out; later aliased as H)
//   region @ 128 MiB    : 64 MiB — embb (phase 1), then FF bf16 (phase 2)
//   w1t    @ 192 MiB    : 1 MiB — dead after gemm1; aliased by small buffers
//   w2t    @ 193 MiB    : 1 MiB — dead after gemm2
// ---------------------------------------------------------------------------
extern "C" void kernel_launch(void* const* d_in, const int* in_sizes, int n_in,
                              void* d_out, int out_size, void* d_ws, size_t ws_size,
                              hipStream_t stream) {
  const int* seq = (const int*)d_in[0];
  const float* emb = (const float*)d_in[1];
  const float* w1 = (const float*)d_in[2];
  const float* b1 = (const float*)d_in[3];
  const float* w2 = (const float*)d_in[4];
  const float* b2 = (const float*)d_in[5];
  const float* ln_g = (const float*)d_in[6];
  const float* ln_b = (const float*)d_in[7];
  const float* wg = (const float*)d_in[8];
  const float* bg = (const float*)d_in[9];
  const float* wq = (const float*)d_in[10];
  const float* bq = (const float*)d_in[11];
  const float* wo = (const float*)d_in[12];
  const float* bo = (const float*)d_in[13];
  float* out = (float*)d_out;

  char* ws = (char*)d_ws;
  unsigned short* A1 = (unsigned short*)ws;                       // 128 MiB
  unsigned short* region = (unsigned short*)(ws + ((size_t)128 << 20));
  unsigned short* embb = region;                                  // phase 1
  unsigned short* FF = region;                                    // phase 2
  unsigned short* w1t = (unsigned short*)(ws + ((size_t)192 << 20));
  unsigned short* w2t = (unsigned short*)(ws + ((size_t)193 << 20));
  char* sb = ws + ((size_t)192 << 20);
  float* gate = (float*)sb;                                       // 256 KiB
  int* topidx = (int*)(sb + 262144);                              // 16 KiB
  float* hlast = (float*)(sb + 262144 + 16384);                   // 32 KiB
  float* qbuf = (float*)(sb + 262144 + 16384 + 32768);            // 32 KiB
  float* ctxbuf = (float*)(sb + 262144 + 16384 + 65536);          // 32 KiB
  unsigned short* H = A1;                                         // A1 dead after gemm2

  cvt_kernel<<<8000, 256, 0, stream>>>(emb, embb);
  wt_kernel<<<4096, 256, 0, stream>>>(w1, w2, w1t, w2t);
  gemm_kernel<512, 1024, 8, true, true>
      <<<4096, 256, 0, stream>>>(seq, embb, w1t, b1, A1);
  gemm_kernel<1024, 512, 4, false, false>
      <<<2048, 256, 0, stream>>>(nullptr, A1, w2t, b2, FF);
  ln_gate_kernel<<<16384, 256, 0, stream>>>(seq, emb, FF, H, ln_g, ln_b, wg, bg, gate, hlast);
  topk_kernel<<<16, 256, 0, stream>>>(gate, topidx);
  q_kernel<<<16, 512, 0, stream>>>(hlast, wq, bq, qbuf);
  attn_kernel<<<16, 256, 0, stream>>>(H, qbuf, topidx, ctxbuf);
  out_kernel<<<125, 256, 0, stream>>>(ctxbuf, wo, bo, out);
}